// Round 11
// baseline (233.023 us; speedup 1.0000x reference)
//
#include <hip/hip_runtime.h>
#include <stdint.h>

#define BATCH 8
#define CH    256
#define NN    2304   // 48*48
#define KVB   64

typedef __bf16 bf16x8 __attribute__((ext_vector_type(8)));
typedef float  f32x4  __attribute__((ext_vector_type(4)));
typedef unsigned short u16x8 __attribute__((ext_vector_type(8)));
typedef unsigned int   u32x4 __attribute__((ext_vector_type(4)));

static __device__ inline unsigned short f2bf(float f) {
    __bf16 h = (__bf16)f;
    return __builtin_bit_cast(unsigned short, h);
}
static __device__ inline unsigned pk2(float a, float b) {
    return (unsigned)f2bf(a) | ((unsigned)f2bf(b) << 16);
}
static __device__ inline float bf2f(unsigned short u) {
    unsigned v = (unsigned)u << 16;
    return __builtin_bit_cast(float, v);
}

#define GLOAD_LDS(gp, lp) __builtin_amdgcn_global_load_lds( \
    (const __attribute__((address_space(1))) unsigned int*)(gp), \
    (__attribute__((address_space(3))) unsigned int*)(lp), 16, 0, 0)

// ---------------- Kernel T: transpose+cast x -> Xt[b][n][c] bf16 ; cast W ----------------
__global__ __launch_bounds__(256) void ktrans(
    const float* __restrict__ x, const float* __restrict__ Ww,
    unsigned short* __restrict__ Xt, unsigned short* __restrict__ Wbf)
{
    const int bid = blockIdx.x;
    const int t   = threadIdx.x;
    const int TPB = 4 * 36; // 64c x 64n tiles per batch
    if (bid >= BATCH * TPB) {
        const int wb = bid - BATCH * TPB;          // 0..7
        const int base = wb * 8192 + t;
        #pragma unroll
        for (int i = 0; i < 32; ++i)
            Wbf[base + i * 256] = f2bf(Ww[base + i * 256]);
        return;
    }
    const int b    = bid / TPB;
    const int tile = bid % TPB;
    const int c0   = (tile / 36) * 64;
    const int n0   = (tile % 36) * 64;
    __shared__ float ld[64][65];
    {
        const int row = t >> 2, seg = t & 3;
        const float* src = x + ((size_t)b * CH + c0 + row) * NN + n0 + seg * 16;
        #pragma unroll
        for (int q = 0; q < 4; ++q) {
            float4 v = *reinterpret_cast<const float4*>(src + q * 4);
            ld[row][seg * 16 + q * 4 + 0] = v.x;
            ld[row][seg * 16 + q * 4 + 1] = v.y;
            ld[row][seg * 16 + q * 4 + 2] = v.z;
            ld[row][seg * 16 + q * 4 + 3] = v.w;
        }
    }
    __syncthreads();
    {
        const int j = t >> 2, cs = t & 3;
        u16x8 v0, v1;
        #pragma unroll
        for (int k = 0; k < 8; ++k) v0[k] = f2bf(ld[cs * 16 + k][j]);
        #pragma unroll
        for (int k = 0; k < 8; ++k) v1[k] = f2bf(ld[cs * 16 + 8 + k][j]);
        unsigned short* dst = Xt + ((size_t)b * NN + n0 + j) * CH + c0 + cs * 16;
        *reinterpret_cast<u16x8*>(dst)     = v0;
        *reinterpret_cast<u16x8*>(dst + 8) = v1;
    }
}

// ---------------- Kernel C: Zc[b][o][n] = sum_c W[o][c] x[b][c][n]  (bf16 out) ----------------
__global__ __launch_bounds__(256) void kconv(
    const unsigned short* __restrict__ Xt,
    const unsigned short* __restrict__ Wb,
    unsigned short* __restrict__ Zc)
{
    const int bid  = blockIdx.x;   // 288 = 8b * 4ot * 9nt
    const int b    = bid & 7;
    const int rest = bid >> 3;     // 0..35
    const int ot   = rest / 9;
    const int nt   = rest % 9;
    const int tid  = threadIdx.x;
    const int lane = tid & 63, w = tid >> 6;
    const int lr = lane & 15, lg = lane >> 4;
    const int ob = ot * 64;
    const int nb = nt * 256 + w * 64;

    f32x4 acc[4][4];
    f32x4 z = {0.f, 0.f, 0.f, 0.f};
    #pragma unroll
    for (int og = 0; og < 4; ++og)
        #pragma unroll
        for (int ng = 0; ng < 4; ++ng) acc[og][ng] = z;

    const unsigned short* wp = Wb + (size_t)(ob + lr) * CH + lg * 8;
    const unsigned short* xp = Xt + ((size_t)b * NN + nb + lr) * CH + lg * 8;
    #pragma unroll 1
    for (int kc = 0; kc < 8; ++kc) {
        bf16x8 af[4], bf[4];
        #pragma unroll
        for (int og = 0; og < 4; ++og)
            af[og] = *reinterpret_cast<const bf16x8*>(wp + (size_t)og * 16 * CH + kc * 32);
        #pragma unroll
        for (int ng = 0; ng < 4; ++ng)
            bf[ng] = *reinterpret_cast<const bf16x8*>(xp + (size_t)ng * 16 * CH + kc * 32);
        #pragma unroll
        for (int og = 0; og < 4; ++og)
            #pragma unroll
            for (int ng = 0; ng < 4; ++ng)
                acc[og][ng] = __builtin_amdgcn_mfma_f32_16x16x32_bf16(af[og], bf[ng], acc[og][ng], 0, 0, 0);
    }
    #pragma unroll
    for (int og = 0; og < 4; ++og)
        #pragma unroll
        for (int ng = 0; ng < 4; ++ng)
            #pragma unroll
            for (int r = 0; r < 4; ++r)
                Zc[((size_t)b * CH + ob + og * 16 + lg * 4 + r) * NN + nb + ng * 16 + lr] =
                    f2bf(acc[og][ng][r]);
}

// pack P^T B-fragment from s-regs (verified shuffle net), fixed-shift softmax
static __device__ inline bf16x8 packP(f32x4 s0, f32x4 s1, float sd, float& lsum,
                                      int lr, int lg) {
    float p0[4], p1[4];
    #pragma unroll
    for (int r = 0; r < 4; ++r) {
        p0[r] = __expf(s0[r] - sd);
        p1[r] = __expf(s1[r] - sd);
        lsum += p0[r] + p1[r];
    }
    unsigned u0 = pk2(p0[0], p0[1]), u1 = pk2(p0[2], p0[3]);
    unsigned u2 = pk2(p1[0], p1[1]), u3 = pk2(p1[2], p1[3]);
    int s0l = lr + ((lg & 1) << 5);
    unsigned a0 = (unsigned)__shfl((int)u0, s0l),      c0 = (unsigned)__shfl((int)u2, s0l);
    unsigned a1 = (unsigned)__shfl((int)u1, s0l),      c1 = (unsigned)__shfl((int)u3, s0l);
    unsigned a2 = (unsigned)__shfl((int)u0, s0l + 16), c2 = (unsigned)__shfl((int)u2, s0l + 16);
    unsigned a3 = (unsigned)__shfl((int)u1, s0l + 16), c3 = (unsigned)__shfl((int)u3, s0l + 16);
    bool hi = (lg >= 2);
    u32x4 pw;
    pw[0] = hi ? c0 : a0;
    pw[1] = hi ? c1 : a1;
    pw[2] = hi ? c2 : a2;
    pw[3] = hi ? c3 : a3;
    return __builtin_bit_cast(bf16x8, pw);
}

// ---------------- Kernel A: flash attention, fixed-shift softmax, 32q/wave, KVB=64 ----------------
// Single 64KB LDS buffer (K 64x512B, V 256x128B); two 32-key compute phases per
// stage/sync pair (halves the per-iteration barrier+drain tax, R8 discipline).
// blocks = 8b * 18qt * nsplit; 4 waves * 32q = 128q per block.
__global__ __launch_bounds__(256, 2) void kattn(
    const unsigned short* __restrict__ Xt,
    const unsigned short* __restrict__ Zc,
    unsigned* __restrict__ pA32,
    float* __restrict__ pL,
    int hshift)
{
    __shared__ __attribute__((aligned(16))) unsigned char smem[65536];

    const int bid  = blockIdx.x;
    const int b    = bid & 7;      // batch -> XCD pin
    const int r    = bid >> 3;
    const int qt   = r >> hshift;             // 0..17
    const int h    = r & ((1 << hshift) - 1); // kv part
    const int kvh  = NN >> hshift;            // keys per part
    const int nit  = kvh >> 6;                // iterations of 64 keys
    const int tid  = threadIdx.x;
    const int lane = tid & 63;
    const int w    = tid >> 6;     // wave 0..3
    const int lr = lane & 15;
    const int lg = lane >> 4;
    const int qbase = qt * 128 + w * 32;

    const unsigned short* xtb = Xt + (size_t)b * NN * CH;
    const char* kSrc = (const char*)xtb + (size_t)h * kvh * 512;
    const char* vSrc = (const char*)(Zc + (size_t)b * CH * NN) + (size_t)h * kvh * 2;

    // per-lane staging offsets: linear LDS dest + inverse-swizzled global src (rule #21)
    int koff[8], voff[8];
    #pragma unroll
    for (int i = 0; i < 8; ++i) {
        int p = w * 8192 + i * 1024 + lane * 16;
        int krow = p >> 9, kc_ = p & 511;              // K tile: 64 rows x 512B
        koff[i] = krow * 512 + (kc_ ^ ((krow & 15) << 4));
        int o = p >> 7, vc = p & 127;                  // V tile: 256 rows x 128B
        voff[i] = o * 4608 + (vc ^ ((o & 7) << 4));
    }

    // Q fragments for two 16q subtiles
    bf16x8 qa0[8], qa1[8];
    {
        const unsigned short* qp0 = xtb + (size_t)(qbase + lr) * CH + lg * 8;
        const unsigned short* qp1 = xtb + (size_t)(qbase + 16 + lr) * CH + lg * 8;
        #pragma unroll
        for (int kc = 0; kc < 8; ++kc) {
            qa0[kc] = *reinterpret_cast<const bf16x8*>(qp0 + kc * 32);
            qa1[kc] = *reinterpret_cast<const bf16x8*>(qp1 + kc * 32);
        }
    }
    // fixed softmax shift: sd[t] = ||q||^2 computed from the SAME bf16 fragments
    float sd0 = 0.f, sd1 = 0.f;
    #pragma unroll
    for (int kc = 0; kc < 8; ++kc)
        #pragma unroll
        for (int j = 0; j < 8; ++j) {
            float v0 = (float)qa0[kc][j];
            float v1 = (float)qa1[kc][j];
            sd0 = fmaf(v0, v0, sd0);
            sd1 = fmaf(v1, v1, sd1);
        }
    sd0 += __shfl_xor(sd0, 16); sd0 += __shfl_xor(sd0, 32);
    sd1 += __shfl_xor(sd1, 16); sd1 += __shfl_xor(sd1, 32);

    f32x4 acc0[16], acc1[16];
    f32x4 zz = {0.f, 0.f, 0.f, 0.f};
    #pragma unroll
    for (int og = 0; og < 16; ++og) { acc0[og] = zz; acc1[og] = zz; }
    float ls0 = 0.f, ls1 = 0.f;

    const int kx  = lr << 4;            // K swizzle: ^((row&15)<<4), row===lr (mod16)
    const int vxm = (lr & 7) << 4;      // V swizzle: ^((o&7)<<4),  o===lr (mod8)

    // ---- stage 64-key tile ti (16 global_load_lds per wave) ----
    #define STAGE(ti) do {                                                  \
        const char* ks_ = kSrc + (size_t)(ti) * (KVB * 512);                \
        const char* vs_ = vSrc + (size_t)(ti) * (KVB * 2);                  \
        unsigned char* kb_ = &smem[w * 8192];                               \
        unsigned char* vb_ = &smem[32768 + w * 8192];                       \
        _Pragma("unroll")                                                   \
        for (int i = 0; i < 8; ++i) GLOAD_LDS(ks_ + koff[i], kb_ + i * 1024); \
        _Pragma("unroll")                                                   \
        for (int i = 0; i < 8; ++i) GLOAD_LDS(vs_ + voff[i], vb_ + i * 1024); \
    } while (0)

    // ---- compute keys [c*32, c*32+32) of the staged tile ----
    #define COMPUTE(c) do {                                                 \
        const unsigned char* kbuf = smem + (c) * 32 * 512;                  \
        const unsigned char* vbuf = smem + 32768;                           \
        f32x4 s00 = zz, s01 = zz, s10 = zz, s11 = zz;                       \
        _Pragma("unroll")                                                   \
        for (int kc = 0; kc < 8; ++kc) {                                    \
            bf16x8 k0 = *reinterpret_cast<const bf16x8*>(kbuf + lr * 512        + ((lg * 16 + kc * 64) ^ kx)); \
            bf16x8 k1 = *reinterpret_cast<const bf16x8*>(kbuf + (lr + 16) * 512 + ((lg * 16 + kc * 64) ^ kx)); \
            s00 = __builtin_amdgcn_mfma_f32_16x16x32_bf16(k0, qa0[kc], s00, 0, 0, 0); \
            s01 = __builtin_amdgcn_mfma_f32_16x16x32_bf16(k1, qa0[kc], s01, 0, 0, 0); \
            s10 = __builtin_amdgcn_mfma_f32_16x16x32_bf16(k0, qa1[kc], s10, 0, 0, 0); \
            s11 = __builtin_amdgcn_mfma_f32_16x16x32_bf16(k1, qa1[kc], s11, 0, 0, 0); \
        }                                                                   \
        bf16x8 pb0 = packP(s00, s01, sd0, ls0, lr, lg);                     \
        bf16x8 pb1 = packP(s10, s11, sd1, ls1, lr, lg);                     \
        _Pragma("unroll")                                                   \
        for (int og = 0; og < 16; ++og) {                                   \
            bf16x8 vb = *reinterpret_cast<const bf16x8*>(vbuf + (og * 16 + lr) * 128 + (((c) * 64 + lg * 16) ^ vxm)); \
            acc0[og] = __builtin_amdgcn_mfma_f32_16x16x32_bf16(vb, pb0, acc0[og], 0, 0, 0); \
            acc1[og] = __builtin_amdgcn_mfma_f32_16x16x32_bf16(vb, pb1, acc1[og], 0, 0, 0); \
        }                                                                   \
    } while (0)

    // prologue
    STAGE(0);
    __syncthreads();

    #pragma unroll 1
    for (int ti = 0; ti < nit; ++ti) {
        COMPUTE(0);
        COMPUTE(1);
        __syncthreads();   // all waves done reading this tile
        if (ti + 1 < nit) STAGE(ti + 1);
        __syncthreads();   // staged data visible
    }
    #undef STAGE
    #undef COMPUTE

    // reduce per-lane partial l over the 4 lane-groups (order-free: fixed shift)
    ls0 += __shfl_xor(ls0, 16); ls0 += __shfl_xor(ls0, 32);
    ls1 += __shfl_xor(ls1, 16); ls1 += __shfl_xor(ls1, 32);

    // write partials
    if (lg == 0) {
        pL[(size_t)(h * 8 + b) * NN + qbase + lr]      = ls0;
        pL[(size_t)(h * 8 + b) * NN + qbase + 16 + lr] = ls1;
    }
    // packed u32 store: within each 32-q chunk, u32 index lr holds (sub0, sub1) = (n=lr, n=16+lr)
    const size_t rowbase = (size_t)(h * 8 + b) * 256;
    const int ub = (qbase >> 1) + lr;   // u32 index within row
    #pragma unroll
    for (int og = 0; og < 16; ++og) {
        #pragma unroll
        for (int rr = 0; rr < 4; ++rr) {
            const int o = og * 16 + lg * 4 + rr;
            pA32[(rowbase + o) * (NN / 2) + ub] = pk2(acc0[og][rr], acc1[og][rr]);
        }
    }
}

// ---------------- Kernel M: out = (sum_c A_c)/(sum_c L_c) + bias + x  (vectorized) ----------------
__global__ __launch_bounds__(192) void kmerge(
    const unsigned* __restrict__ pA32, const float* __restrict__ pL,
    const float* __restrict__ x, const float* __restrict__ bias,
    float* __restrict__ out, int nsplit)
{
    const int b = blockIdx.x >> 8;
    const int o = blockIdx.x & 255;
    const float bo = bias[o];
    const size_t xb = ((size_t)b * 256 + o) * NN;
    #pragma unroll
    for (int k = 0; k < 3; ++k) {
        const int quad = k * 192 + threadIdx.x;   // 0..575
        const int n = quad * 4;
        // permuted layout: u32 idx = row*(NN/2) + (n>>5)*16 + (n&15); half = (n>>4)&1
        const int ui = (n >> 5) * 16 + (n & 15);
        const int hi = (n >> 4) & 1;
        float v0 = 0.f, v1 = 0.f, v2 = 0.f, v3 = 0.f;
        float l0 = 0.f, l1 = 0.f, l2 = 0.f, l3 = 0.f;
        for (int c = 0; c < nsplit; ++c) {
            const size_t row = ((size_t)(c * 8 + b)) * 256 + o;
            u32x4 pv = *reinterpret_cast<const u32x4*>(pA32 + row * (NN / 2) + ui);
            v0 += bf2f((unsigned short)(hi ? (pv[0] >> 16) : (pv[0] & 0xffff)));
            v1 += bf2f((unsigned short)(hi ? (pv[1] >> 16) : (pv[1] & 0xffff)));
            v2 += bf2f((unsigned short)(hi ? (pv[2] >> 16) : (pv[2] & 0xffff)));
            v3 += bf2f((unsigned short)(hi ? (pv[3] >> 16) : (pv[3] & 0xffff)));
            float4 lv = *reinterpret_cast<const float4*>(pL + ((size_t)(c * 8 + b)) * NN + n);
            l0 += lv.x; l1 += lv.y; l2 += lv.z; l3 += lv.w;
        }
        float4 xv = *reinterpret_cast<const float4*>(x + xb + n);
        float4 ov;
        ov.x = v0 / l0 + bo + xv.x;
        ov.y = v1 / l1 + bo + xv.y;
        ov.z = v2 / l2 + bo + xv.z;
        ov.w = v3 / l3 + bo + xv.w;
        *reinterpret_cast<float4*>(out + xb + n) = ov;
    }
}

extern "C" void kernel_launch(void* const* d_in, const int* in_sizes, int n_in,
                              void* d_out, int out_size, void* d_ws, size_t ws_size,
                              hipStream_t stream) {
    const float* x    = (const float*)d_in[0];
    const float* Ww   = (const float*)d_in[1];
    const float* bias = (const float*)d_in[2];
    float* out = (float*)d_out;

    unsigned short* Xt  = (unsigned short*)d_ws;                 // B*N*C bf16   (9,437,184 B)
    unsigned short* Zc  = Xt + (size_t)BATCH * NN * CH;          // B*C*N bf16   (9,437,184 B)
    unsigned short* Wbf = Zc + (size_t)BATCH * NN * CH;          // C*C bf16     (131,072 B)
    unsigned*       pA32 = (unsigned*)(Wbf + (size_t)CH * CH);   // nsplit*B*C*(N/2) u32

    const size_t base = (size_t)9437184 * 2 + 131072;
    const size_t perSplit = (size_t)BATCH * CH * NN * 2   // pA
                          + (size_t)BATCH * NN * 4;       // pL
    int hshift;
    if (ws_size >= base + 4 * perSplit) hshift = 2;       // split-4 (nit=9)
    else                                hshift = 1;       // split-2 (nit=18)
    const int nsplit = 1 << hshift;
    float* pL = (float*)(pA32 + (size_t)nsplit * BATCH * CH * (NN / 2));

    ktrans<<<8 * 144 + 8,       256, 0, stream>>>(x, Ww, Xt, Wbf);
    kconv <<<288,               256, 0, stream>>>(Xt, Wbf, Zc);
    kattn <<<8 * 18 * nsplit,   256, 0, stream>>>(Xt, Zc, pA32, pL, hshift);
    kmerge<<<2048,              192, 0, stream>>>(pA32, pL, x, bias, out, nsplit);
}

// Round 12
// 232.864 us; speedup vs baseline: 1.0007x; 1.0007x over previous
//
#include <hip/hip_runtime.h>
#include <stdint.h>

#define BATCH 8
#define CH    256
#define NN    2304   // 48*48
#define KVB   64

typedef __bf16 bf16x8 __attribute__((ext_vector_type(8)));
typedef float  f32x4  __attribute__((ext_vector_type(4)));
typedef unsigned short u16x8 __attribute__((ext_vector_type(8)));
typedef unsigned int   u32x4 __attribute__((ext_vector_type(4)));

static __device__ inline unsigned short f2bf(float f) {
    __bf16 h = (__bf16)f;
    return __builtin_bit_cast(unsigned short, h);
}
static __device__ inline unsigned pk2(float a, float b) {
    return (unsigned)f2bf(a) | ((unsigned)f2bf(b) << 16);
}
static __device__ inline float bf2f(unsigned short u) {
    unsigned v = (unsigned)u << 16;
    return __builtin_bit_cast(float, v);
}

#define GLOAD_LDS(gp, lp) __builtin_amdgcn_global_load_lds( \
    (const __attribute__((address_space(1))) unsigned int*)(gp), \
    (__attribute__((address_space(3))) unsigned int*)(lp), 16, 0, 0)

// ---------------- Kernel T: transpose+cast x -> Xt[b][n][c] bf16 ; cast W ----------------
__global__ __launch_bounds__(256) void ktrans(
    const float* __restrict__ x, const float* __restrict__ Ww,
    unsigned short* __restrict__ Xt, unsigned short* __restrict__ Wbf)
{
    const int bid = blockIdx.x;
    const int t   = threadIdx.x;
    const int TPB = 4 * 36; // 64c x 64n tiles per batch
    if (bid >= BATCH * TPB) {
        const int wb = bid - BATCH * TPB;          // 0..7
        const int base = wb * 8192 + t;
        #pragma unroll
        for (int i = 0; i < 32; ++i)
            Wbf[base + i * 256] = f2bf(Ww[base + i * 256]);
        return;
    }
    const int b    = bid / TPB;
    const int tile = bid % TPB;
    const int c0   = (tile / 36) * 64;
    const int n0   = (tile % 36) * 64;
    __shared__ float ld[64][65];
    {
        const int row = t >> 2, seg = t & 3;
        const float* src = x + ((size_t)b * CH + c0 + row) * NN + n0 + seg * 16;
        #pragma unroll
        for (int q = 0; q < 4; ++q) {
            float4 v = *reinterpret_cast<const float4*>(src + q * 4);
            ld[row][seg * 16 + q * 4 + 0] = v.x;
            ld[row][seg * 16 + q * 4 + 1] = v.y;
            ld[row][seg * 16 + q * 4 + 2] = v.z;
            ld[row][seg * 16 + q * 4 + 3] = v.w;
        }
    }
    __syncthreads();
    {
        const int j = t >> 2, cs = t & 3;
        u16x8 v0, v1;
        #pragma unroll
        for (int k = 0; k < 8; ++k) v0[k] = f2bf(ld[cs * 16 + k][j]);
        #pragma unroll
        for (int k = 0; k < 8; ++k) v1[k] = f2bf(ld[cs * 16 + 8 + k][j]);
        unsigned short* dst = Xt + ((size_t)b * NN + n0 + j) * CH + c0 + cs * 16;
        *reinterpret_cast<u16x8*>(dst)     = v0;
        *reinterpret_cast<u16x8*>(dst + 8) = v1;
    }
}

// ---------------- Kernel C: Zc[b][o][n] = sum_c W[o][c] x[b][c][n]  (bf16 out) ----------------
__global__ __launch_bounds__(256) void kconv(
    const unsigned short* __restrict__ Xt,
    const unsigned short* __restrict__ Wb,
    unsigned short* __restrict__ Zc)
{
    const int bid  = blockIdx.x;   // 288 = 8b * 4ot * 9nt
    const int b    = bid & 7;
    const int rest = bid >> 3;     // 0..35
    const int ot   = rest / 9;
    const int nt   = rest % 9;
    const int tid  = threadIdx.x;
    const int lane = tid & 63, w = tid >> 6;
    const int lr = lane & 15, lg = lane >> 4;
    const int ob = ot * 64;
    const int nb = nt * 256 + w * 64;

    f32x4 acc[4][4];
    f32x4 z = {0.f, 0.f, 0.f, 0.f};
    #pragma unroll
    for (int og = 0; og < 4; ++og)
        #pragma unroll
        for (int ng = 0; ng < 4; ++ng) acc[og][ng] = z;

    const unsigned short* wp = Wb + (size_t)(ob + lr) * CH + lg * 8;
    const unsigned short* xp = Xt + ((size_t)b * NN + nb + lr) * CH + lg * 8;
    #pragma unroll 1
    for (int kc = 0; kc < 8; ++kc) {
        bf16x8 af[4], bf[4];
        #pragma unroll
        for (int og = 0; og < 4; ++og)
            af[og] = *reinterpret_cast<const bf16x8*>(wp + (size_t)og * 16 * CH + kc * 32);
        #pragma unroll
        for (int ng = 0; ng < 4; ++ng)
            bf[ng] = *reinterpret_cast<const bf16x8*>(xp + (size_t)ng * 16 * CH + kc * 32);
        #pragma unroll
        for (int og = 0; og < 4; ++og)
            #pragma unroll
            for (int ng = 0; ng < 4; ++ng)
                acc[og][ng] = __builtin_amdgcn_mfma_f32_16x16x32_bf16(af[og], bf[ng], acc[og][ng], 0, 0, 0);
    }
    #pragma unroll
    for (int og = 0; og < 4; ++og)
        #pragma unroll
        for (int ng = 0; ng < 4; ++ng)
            #pragma unroll
            for (int r = 0; r < 4; ++r)
                Zc[((size_t)b * CH + ob + og * 16 + lg * 4 + r) * NN + nb + ng * 16 + lr] =
                    f2bf(acc[og][ng][r]);
}

// pack P^T B-fragment from s-regs (verified shuffle net), fixed-shift softmax
static __device__ inline bf16x8 packP(f32x4 s0, f32x4 s1, float sd, float& lsum,
                                      int lr, int lg) {
    float p0[4], p1[4];
    #pragma unroll
    for (int r = 0; r < 4; ++r) {
        p0[r] = __expf(s0[r] - sd);
        p1[r] = __expf(s1[r] - sd);
        lsum += p0[r] + p1[r];
    }
    unsigned u0 = pk2(p0[0], p0[1]), u1 = pk2(p0[2], p0[3]);
    unsigned u2 = pk2(p1[0], p1[1]), u3 = pk2(p1[2], p1[3]);
    int s0l = lr + ((lg & 1) << 5);
    unsigned a0 = (unsigned)__shfl((int)u0, s0l),      c0 = (unsigned)__shfl((int)u2, s0l);
    unsigned a1 = (unsigned)__shfl((int)u1, s0l),      c1 = (unsigned)__shfl((int)u3, s0l);
    unsigned a2 = (unsigned)__shfl((int)u0, s0l + 16), c2 = (unsigned)__shfl((int)u2, s0l + 16);
    unsigned a3 = (unsigned)__shfl((int)u1, s0l + 16), c3 = (unsigned)__shfl((int)u3, s0l + 16);
    bool hi = (lg >= 2);
    u32x4 pw;
    pw[0] = hi ? c0 : a0;
    pw[1] = hi ? c1 : a1;
    pw[2] = hi ? c2 : a2;
    pw[3] = hi ? c3 : a3;
    return __builtin_bit_cast(bf16x8, pw);
}

// ---------------- Kernel A: flash attention, fixed-shift softmax, 32q/wave, KVB=64 ----------------
// Single 64KB LDS buffer (K 64x512B, V 256x128B); two 32-key compute phases per
// stage/sync pair (halves the per-iteration barrier+drain tax, R8 discipline).
// blocks = 8b * 18qt * nsplit; 4 waves * 32q = 128q per block.
__global__ __launch_bounds__(256, 2) void kattn(
    const unsigned short* __restrict__ Xt,
    const unsigned short* __restrict__ Zc,
    unsigned* __restrict__ pA32,
    float* __restrict__ pL,
    int hshift)
{
    __shared__ __attribute__((aligned(16))) unsigned char smem[65536];

    const int bid  = blockIdx.x;
    const int b    = bid & 7;      // batch -> XCD pin
    const int r    = bid >> 3;
    const int qt   = r >> hshift;             // 0..17
    const int h    = r & ((1 << hshift) - 1); // kv part
    const int kvh  = NN >> hshift;            // keys per part
    const int nit  = kvh >> 6;                // iterations of 64 keys
    const int tid  = threadIdx.x;
    const int lane = tid & 63;
    const int w    = tid >> 6;     // wave 0..3
    const int lr = lane & 15;
    const int lg = lane >> 4;
    const int qbase = qt * 128 + w * 32;

    const unsigned short* xtb = Xt + (size_t)b * NN * CH;
    const char* kSrc = (const char*)xtb + (size_t)h * kvh * 512;
    const char* vSrc = (const char*)(Zc + (size_t)b * CH * NN) + (size_t)h * kvh * 2;

    // per-lane staging offsets: linear LDS dest + inverse-swizzled global src (rule #21)
    int koff[8], voff[8];
    #pragma unroll
    for (int i = 0; i < 8; ++i) {
        int p = w * 8192 + i * 1024 + lane * 16;
        int krow = p >> 9, kc_ = p & 511;              // K tile: 64 rows x 512B
        koff[i] = krow * 512 + (kc_ ^ ((krow & 15) << 4));
        int o = p >> 7, vc = p & 127;                  // V tile: 256 rows x 128B
        voff[i] = o * 4608 + (vc ^ ((o & 7) << 4));
    }

    // Q fragments for two 16q subtiles
    bf16x8 qa0[8], qa1[8];
    {
        const unsigned short* qp0 = xtb + (size_t)(qbase + lr) * CH + lg * 8;
        const unsigned short* qp1 = xtb + (size_t)(qbase + 16 + lr) * CH + lg * 8;
        #pragma unroll
        for (int kc = 0; kc < 8; ++kc) {
            qa0[kc] = *reinterpret_cast<const bf16x8*>(qp0 + kc * 32);
            qa1[kc] = *reinterpret_cast<const bf16x8*>(qp1 + kc * 32);
        }
    }
    // fixed softmax shift: sd[t] = ||q||^2 computed from the SAME bf16 fragments
    float sd0 = 0.f, sd1 = 0.f;
    #pragma unroll
    for (int kc = 0; kc < 8; ++kc)
        #pragma unroll
        for (int j = 0; j < 8; ++j) {
            float v0 = (float)qa0[kc][j];
            float v1 = (float)qa1[kc][j];
            sd0 = fmaf(v0, v0, sd0);
            sd1 = fmaf(v1, v1, sd1);
        }
    sd0 += __shfl_xor(sd0, 16); sd0 += __shfl_xor(sd0, 32);
    sd1 += __shfl_xor(sd1, 16); sd1 += __shfl_xor(sd1, 32);

    f32x4 acc0[16], acc1[16];
    f32x4 zz = {0.f, 0.f, 0.f, 0.f};
    #pragma unroll
    for (int og = 0; og < 16; ++og) { acc0[og] = zz; acc1[og] = zz; }
    float ls0 = 0.f, ls1 = 0.f;

    const int kx  = lr << 4;            // K swizzle: ^((row&15)<<4), row===lr (mod16)
    const int vxm = (lr & 7) << 4;      // V swizzle: ^((o&7)<<4),  o===lr (mod8)

    // ---- stage 64-key tile ti (16 global_load_lds per wave) ----
    #define STAGE(ti) do {                                                  \
        const char* ks_ = kSrc + (size_t)(ti) * (KVB * 512);                \
        const char* vs_ = vSrc + (size_t)(ti) * (KVB * 2);                  \
        unsigned char* kb_ = &smem[w * 8192];                               \
        unsigned char* vb_ = &smem[32768 + w * 8192];                       \
        _Pragma("unroll")                                                   \
        for (int i = 0; i < 8; ++i) GLOAD_LDS(ks_ + koff[i], kb_ + i * 1024); \
        _Pragma("unroll")                                                   \
        for (int i = 0; i < 8; ++i) GLOAD_LDS(vs_ + voff[i], vb_ + i * 1024); \
    } while (0)

    // ---- compute keys [c*32, c*32+32) of the staged tile ----
    #define COMPUTE(c) do {                                                 \
        const unsigned char* kbuf = smem + (c) * 32 * 512;                  \
        const unsigned char* vbuf = smem + 32768;                           \
        f32x4 s00 = zz, s01 = zz, s10 = zz, s11 = zz;                       \
        _Pragma("unroll")                                                   \
        for (int kc = 0; kc < 8; ++kc) {                                    \
            bf16x8 k0 = *reinterpret_cast<const bf16x8*>(kbuf + lr * 512        + ((lg * 16 + kc * 64) ^ kx)); \
            bf16x8 k1 = *reinterpret_cast<const bf16x8*>(kbuf + (lr + 16) * 512 + ((lg * 16 + kc * 64) ^ kx)); \
            s00 = __builtin_amdgcn_mfma_f32_16x16x32_bf16(k0, qa0[kc], s00, 0, 0, 0); \
            s01 = __builtin_amdgcn_mfma_f32_16x16x32_bf16(k1, qa0[kc], s01, 0, 0, 0); \
            s10 = __builtin_amdgcn_mfma_f32_16x16x32_bf16(k0, qa1[kc], s10, 0, 0, 0); \
            s11 = __builtin_amdgcn_mfma_f32_16x16x32_bf16(k1, qa1[kc], s11, 0, 0, 0); \
        }                                                                   \
        bf16x8 pb0 = packP(s00, s01, sd0, ls0, lr, lg);                     \
        bf16x8 pb1 = packP(s10, s11, sd1, ls1, lr, lg);                     \
        _Pragma("unroll")                                                   \
        for (int og = 0; og < 16; ++og) {                                   \
            bf16x8 vb = *reinterpret_cast<const bf16x8*>(vbuf + (og * 16 + lr) * 128 + (((c) * 64 + lg * 16) ^ vxm)); \
            acc0[og] = __builtin_amdgcn_mfma_f32_16x16x32_bf16(vb, pb0, acc0[og], 0, 0, 0); \
            acc1[og] = __builtin_amdgcn_mfma_f32_16x16x32_bf16(vb, pb1, acc1[og], 0, 0, 0); \
        }                                                                   \
    } while (0)

    // prologue
    STAGE(0);
    __syncthreads();

    #pragma unroll 1
    for (int ti = 0; ti < nit; ++ti) {
        COMPUTE(0);
        COMPUTE(1);
        __syncthreads();   // all waves done reading this tile
        if (ti + 1 < nit) STAGE(ti + 1);
        __syncthreads();   // staged data visible
    }
    #undef STAGE
    #undef COMPUTE

    // reduce per-lane partial l over the 4 lane-groups (order-free: fixed shift)
    ls0 += __shfl_xor(ls0, 16); ls0 += __shfl_xor(ls0, 32);
    ls1 += __shfl_xor(ls1, 16); ls1 += __shfl_xor(ls1, 32);

    // write partials
    if (lg == 0) {
        pL[(size_t)(h * 8 + b) * NN + qbase + lr]      = ls0;
        pL[(size_t)(h * 8 + b) * NN + qbase + 16 + lr] = ls1;
    }
    // packed u32 store: within each 32-q chunk, u32 index lr holds (sub0, sub1) = (n=lr, n=16+lr)
    const size_t rowbase = (size_t)(h * 8 + b) * 256;
    const int ub = (qbase >> 1) + lr;   // u32 index within row
    #pragma unroll
    for (int og = 0; og < 16; ++og) {
        #pragma unroll
        for (int rr = 0; rr < 4; ++rr) {
            const int o = og * 16 + lg * 4 + rr;
            pA32[(rowbase + o) * (NN / 2) + ub] = pk2(acc0[og][rr], acc1[og][rr]);
        }
    }
}

// ---------------- Kernel M: out = (sum_c A_c)/(sum_c L_c) + bias + x  (vectorized) ----------------
__global__ __launch_bounds__(192) void kmerge(
    const unsigned* __restrict__ pA32, const float* __restrict__ pL,
    const float* __restrict__ x, const float* __restrict__ bias,
    float* __restrict__ out, int nsplit)
{
    const int b = blockIdx.x >> 8;
    const int o = blockIdx.x & 255;
    const float bo = bias[o];
    const size_t xb = ((size_t)b * 256 + o) * NN;
    #pragma unroll
    for (int k = 0; k < 3; ++k) {
        const int quad = k * 192 + threadIdx.x;   // 0..575
        const int n = quad * 4;
        // permuted layout: u32 idx = row*(NN/2) + (n>>5)*16 + (n&15); half = (n>>4)&1
        const int ui = (n >> 5) * 16 + (n & 15);
        const int hi = (n >> 4) & 1;
        float v0 = 0.f, v1 = 0.f, v2 = 0.f, v3 = 0.f;
        float l0 = 0.f, l1 = 0.f, l2 = 0.f, l3 = 0.f;
        for (int c = 0; c < nsplit; ++c) {
            const size_t row = ((size_t)(c * 8 + b)) * 256 + o;
            u32x4 pv = *reinterpret_cast<const u32x4*>(pA32 + row * (NN / 2) + ui);
            v0 += bf2f((unsigned short)(hi ? (pv[0] >> 16) : (pv[0] & 0xffff)));
            v1 += bf2f((unsigned short)(hi ? (pv[1] >> 16) : (pv[1] & 0xffff)));
            v2 += bf2f((unsigned short)(hi ? (pv[2] >> 16) : (pv[2] & 0xffff)));
            v3 += bf2f((unsigned short)(hi ? (pv[3] >> 16) : (pv[3] & 0xffff)));
            float4 lv = *reinterpret_cast<const float4*>(pL + ((size_t)(c * 8 + b)) * NN + n);
            l0 += lv.x; l1 += lv.y; l2 += lv.z; l3 += lv.w;
        }
        float4 xv = *reinterpret_cast<const float4*>(x + xb + n);
        float4 ov;
        ov.x = v0 / l0 + bo + xv.x;
        ov.y = v1 / l1 + bo + xv.y;
        ov.z = v2 / l2 + bo + xv.z;
        ov.w = v3 / l3 + bo + xv.w;
        *reinterpret_cast<float4*>(out + xb + n) = ov;
    }
}

extern "C" void kernel_launch(void* const* d_in, const int* in_sizes, int n_in,
                              void* d_out, int out_size, void* d_ws, size_t ws_size,
                              hipStream_t stream) {
    const float* x    = (const float*)d_in[0];
    const float* Ww   = (const float*)d_in[1];
    const float* bias = (const float*)d_in[2];
    float* out = (float*)d_out;

    unsigned short* Xt  = (unsigned short*)d_ws;                 // B*N*C bf16   (9,437,184 B)
    unsigned short* Zc  = Xt + (size_t)BATCH * NN * CH;          // B*C*N bf16   (9,437,184 B)
    unsigned short* Wbf = Zc + (size_t)BATCH * NN * CH;          // C*C bf16     (131,072 B)
    unsigned*       pA32 = (unsigned*)(Wbf + (size_t)CH * CH);   // nsplit*B*C*(N/2) u32

    const size_t base = (size_t)9437184 * 2 + 131072;
    const size_t perSplit = (size_t)BATCH * CH * NN * 2   // pA
                          + (size_t)BATCH * NN * 4;       // pL
    int hshift;
    if (ws_size >= base + 4 * perSplit) hshift = 2;       // split-4 (nit=9)
    else                                hshift = 1;       // split-2 (nit=18)
    const int nsplit = 1 << hshift;
    float* pL = (float*)(pA32 + (size_t)nsplit * BATCH * CH * (NN / 2));

    ktrans<<<8 * 144 + 8,       256, 0, stream>>>(x, Ww, Xt, Wbf);
    kconv <<<288,               256, 0, stream>>>(Xt, Wbf, Zc);
    kattn <<<8 * 18 * nsplit,   256, 0, stream>>>(Xt, Zc, pA32, pL, hshift);
    kmerge<<<2048,              192, 0, stream>>>(pA32, pL, x, bias, out, nsplit);
}

// Round 13
// 123.587 us; speedup vs baseline: 1.8855x; 1.8842x over previous
//
#include <hip/hip_runtime.h>
#include <stdint.h>

#define BATCH 8
#define CH    256
#define NN    2304   // 48*48
#define KVB   32

typedef __bf16 bf16x8 __attribute__((ext_vector_type(8)));
typedef float  f32x4  __attribute__((ext_vector_type(4)));
typedef unsigned short u16x8 __attribute__((ext_vector_type(8)));
typedef unsigned int   u32x4 __attribute__((ext_vector_type(4)));

static __device__ inline unsigned short f2bf(float f) {
    __bf16 h = (__bf16)f;
    return __builtin_bit_cast(unsigned short, h);
}
static __device__ inline unsigned pk2(float a, float b) {
    return (unsigned)f2bf(a) | ((unsigned)f2bf(b) << 16);
}
static __device__ inline float bf2f(unsigned short u) {
    unsigned v = (unsigned)u << 16;
    return __builtin_bit_cast(float, v);
}

#define GLOAD_LDS(gp, lp) __builtin_amdgcn_global_load_lds( \
    (const __attribute__((address_space(1))) unsigned int*)(gp), \
    (__attribute__((address_space(3))) unsigned int*)(lp), 16, 0, 0)

// ---------------- Kernel T: transpose+cast x -> Xt[b][n][c] bf16 ; cast W ----------------
__global__ __launch_bounds__(256) void ktrans(
    const float* __restrict__ x, const float* __restrict__ Ww,
    unsigned short* __restrict__ Xt, unsigned short* __restrict__ Wbf)
{
    const int bid = blockIdx.x;
    const int t   = threadIdx.x;
    const int TPB = 4 * 36; // 64c x 64n tiles per batch
    if (bid >= BATCH * TPB) {
        const int wb = bid - BATCH * TPB;          // 0..7
        const int base = wb * 8192 + t;
        #pragma unroll
        for (int i = 0; i < 32; ++i)
            Wbf[base + i * 256] = f2bf(Ww[base + i * 256]);
        return;
    }
    const int b    = bid / TPB;
    const int tile = bid % TPB;
    const int c0   = (tile / 36) * 64;
    const int n0   = (tile % 36) * 64;
    __shared__ float ld[64][65];
    {
        const int row = t >> 2, seg = t & 3;
        const float* src = x + ((size_t)b * CH + c0 + row) * NN + n0 + seg * 16;
        #pragma unroll
        for (int q = 0; q < 4; ++q) {
            float4 v = *reinterpret_cast<const float4*>(src + q * 4);
            ld[row][seg * 16 + q * 4 + 0] = v.x;
            ld[row][seg * 16 + q * 4 + 1] = v.y;
            ld[row][seg * 16 + q * 4 + 2] = v.z;
            ld[row][seg * 16 + q * 4 + 3] = v.w;
        }
    }
    __syncthreads();
    {
        const int j = t >> 2, cs = t & 3;
        u16x8 v0, v1;
        #pragma unroll
        for (int k = 0; k < 8; ++k) v0[k] = f2bf(ld[cs * 16 + k][j]);
        #pragma unroll
        for (int k = 0; k < 8; ++k) v1[k] = f2bf(ld[cs * 16 + 8 + k][j]);
        unsigned short* dst = Xt + ((size_t)b * NN + n0 + j) * CH + c0 + cs * 16;
        *reinterpret_cast<u16x8*>(dst)     = v0;
        *reinterpret_cast<u16x8*>(dst + 8) = v1;
    }
}

// ---------------- Kernel C: Zc[b][o][n] = sum_c W[o][c] x[b][c][n]  (bf16 out) ----------------
__global__ __launch_bounds__(256) void kconv(
    const unsigned short* __restrict__ Xt,
    const unsigned short* __restrict__ Wb,
    unsigned short* __restrict__ Zc)
{
    const int bid  = blockIdx.x;   // 288 = 8b * 4ot * 9nt
    const int b    = bid & 7;
    const int rest = bid >> 3;     // 0..35
    const int ot   = rest / 9;
    const int nt   = rest % 9;
    const int tid  = threadIdx.x;
    const int lane = tid & 63, w = tid >> 6;
    const int lr = lane & 15, lg = lane >> 4;
    const int ob = ot * 64;
    const int nb = nt * 256 + w * 64;

    f32x4 acc[4][4];
    f32x4 z = {0.f, 0.f, 0.f, 0.f};
    #pragma unroll
    for (int og = 0; og < 4; ++og)
        #pragma unroll
        for (int ng = 0; ng < 4; ++ng) acc[og][ng] = z;

    const unsigned short* wp = Wb + (size_t)(ob + lr) * CH + lg * 8;
    const unsigned short* xp = Xt + ((size_t)b * NN + nb + lr) * CH + lg * 8;
    #pragma unroll 1
    for (int kc = 0; kc < 8; ++kc) {
        bf16x8 af[4], bf[4];
        #pragma unroll
        for (int og = 0; og < 4; ++og)
            af[og] = *reinterpret_cast<const bf16x8*>(wp + (size_t)og * 16 * CH + kc * 32);
        #pragma unroll
        for (int ng = 0; ng < 4; ++ng)
            bf[ng] = *reinterpret_cast<const bf16x8*>(xp + (size_t)ng * 16 * CH + kc * 32);
        #pragma unroll
        for (int og = 0; og < 4; ++og)
            #pragma unroll
            for (int ng = 0; ng < 4; ++ng)
                acc[og][ng] = __builtin_amdgcn_mfma_f32_16x16x32_bf16(af[og], bf[ng], acc[og][ng], 0, 0, 0);
    }
    #pragma unroll
    for (int og = 0; og < 4; ++og)
        #pragma unroll
        for (int ng = 0; ng < 4; ++ng)
            #pragma unroll
            for (int r = 0; r < 4; ++r)
                Zc[((size_t)b * CH + ob + og * 16 + lg * 4 + r) * NN + nb + ng * 16 + lr] =
                    f2bf(acc[og][ng][r]);
}

// pack P^T B-fragment from s-regs (verified shuffle net), fixed-shift softmax
static __device__ inline bf16x8 packP(f32x4 s0, f32x4 s1, float sd, float& lsum,
                                      int lr, int lg) {
    float p0[4], p1[4];
    #pragma unroll
    for (int r = 0; r < 4; ++r) {
        p0[r] = __expf(s0[r] - sd);
        p1[r] = __expf(s1[r] - sd);
        lsum += p0[r] + p1[r];
    }
    unsigned u0 = pk2(p0[0], p0[1]), u1 = pk2(p0[2], p0[3]);
    unsigned u2 = pk2(p1[0], p1[1]), u3 = pk2(p1[2], p1[3]);
    int s0l = lr + ((lg & 1) << 5);
    unsigned a0 = (unsigned)__shfl((int)u0, s0l),      c0 = (unsigned)__shfl((int)u2, s0l);
    unsigned a1 = (unsigned)__shfl((int)u1, s0l),      c1 = (unsigned)__shfl((int)u3, s0l);
    unsigned a2 = (unsigned)__shfl((int)u0, s0l + 16), c2 = (unsigned)__shfl((int)u2, s0l + 16);
    unsigned a3 = (unsigned)__shfl((int)u1, s0l + 16), c3 = (unsigned)__shfl((int)u3, s0l + 16);
    bool hi = (lg >= 2);
    u32x4 pw;
    pw[0] = hi ? c0 : a0;
    pw[1] = hi ? c1 : a1;
    pw[2] = hi ? c2 : a2;
    pw[3] = hi ? c3 : a3;
    return __builtin_bit_cast(bf16x8, pw);
}

// ---------------- Kernel A: flash attention, fixed-shift softmax, 32q/wave ----------------
// 2-WAVE blocks (64 q): reg cap 256/wave -> 8 waves/CU = 4 co-resident blocks;
// stage+barrier-drain of one block hides under 3 others' compute (TLP).
// Single 32KB LDS (K 32x512B swz ^((row&15)<<4), V 256x64B swz ^(((o>>1)&3)<<4)),
// staged by 2 waves: 8 stored offsets + swizzle-invariant mirrors (+16 K-rows, +128 V-rows).
// blocks = 8b * 36qt * nsplit.
__global__ __launch_bounds__(128, 2) void kattn(
    const unsigned short* __restrict__ Xt,
    const unsigned short* __restrict__ Zc,
    unsigned* __restrict__ pA32,
    float* __restrict__ pL,
    int hshift)
{
    __shared__ __attribute__((aligned(16))) unsigned char smem[32768];

    const int bid  = blockIdx.x;
    const int b    = bid & 7;      // batch -> XCD pin
    const int r    = bid >> 3;
    const int qt   = r >> hshift;             // 0..35
    const int h    = r & ((1 << hshift) - 1); // kv part
    const int kvh  = NN >> hshift;            // keys per part
    const int nit  = kvh >> 5;                // iterations of 32 keys
    const int tid  = threadIdx.x;
    const int lane = tid & 63;
    const int w    = tid >> 6;     // wave 0..1
    const int lr = lane & 15;
    const int lg = lane >> 4;
    const int qbase = qt * 64 + w * 32;

    const unsigned short* xtb = Xt + (size_t)b * NN * CH;
    const char* kSrc = (const char*)xtb + (size_t)h * kvh * 512;
    const char* vSrc = (const char*)(Zc + (size_t)b * CH * NN) + (size_t)h * kvh * 2;

    // staging offsets: wave w owns 1KB chunks c = 2i+w and c+8 (mirrors).
    // K chunk c covers rows [2c,2c+2); +8 chunks = +16 rows: (krow+16)&15 == krow&15.
    // V chunk c covers rows [16c,16c+16); +8 chunks = +128 rows: ((o+128)>>1)&3 == (o>>1)&3.
    int koff[4], voff[4], kdst[4], vdst[4];
    #pragma unroll
    for (int i = 0; i < 4; ++i) {
        const int c = 2 * i + w;
        const int p = c * 1024 + lane * 16;
        const int krow = p >> 9, kc_ = p & 511;
        koff[i] = krow * 512 + (kc_ ^ ((krow & 15) << 4));
        kdst[i] = c * 1024;
        const int o = p >> 6, vc = p & 63;
        voff[i] = o * 4608 + (vc ^ (((o >> 1) & 3) << 4));
        vdst[i] = 16384 + c * 1024;
    }

    // Q fragments for two 16q subtiles
    bf16x8 qa0[8], qa1[8];
    {
        const unsigned short* qp0 = xtb + (size_t)(qbase + lr) * CH + lg * 8;
        const unsigned short* qp1 = xtb + (size_t)(qbase + 16 + lr) * CH + lg * 8;
        #pragma unroll
        for (int kc = 0; kc < 8; ++kc) {
            qa0[kc] = *reinterpret_cast<const bf16x8*>(qp0 + kc * 32);
            qa1[kc] = *reinterpret_cast<const bf16x8*>(qp1 + kc * 32);
        }
    }
    // fixed softmax shift: sd[t] = ||q||^2 from the SAME bf16 fragments
    float sd0 = 0.f, sd1 = 0.f;
    #pragma unroll
    for (int kc = 0; kc < 8; ++kc)
        #pragma unroll
        for (int j = 0; j < 8; ++j) {
            float v0 = (float)qa0[kc][j];
            float v1 = (float)qa1[kc][j];
            sd0 = fmaf(v0, v0, sd0);
            sd1 = fmaf(v1, v1, sd1);
        }
    sd0 += __shfl_xor(sd0, 16); sd0 += __shfl_xor(sd0, 32);
    sd1 += __shfl_xor(sd1, 16); sd1 += __shfl_xor(sd1, 32);

    f32x4 acc0[16], acc1[16];
    f32x4 zz = {0.f, 0.f, 0.f, 0.f};
    #pragma unroll
    for (int og = 0; og < 16; ++og) { acc0[og] = zz; acc1[og] = zz; }
    float ls0 = 0.f, ls1 = 0.f;

    const int kx = lr << 4;
    const int vx = (lg * 16) ^ (((lr >> 1) & 3) << 4);

    // ---- stage 32-key tile ti (16 global_load_lds per wave, mirror-derived) ----
    #define STAGE(ti) do {                                                  \
        const char* ks_ = kSrc + (size_t)(ti) * (KVB * 512);                \
        const char* vs_ = vSrc + (size_t)(ti) * (KVB * 2);                  \
        _Pragma("unroll")                                                   \
        for (int i = 0; i < 4; ++i) {                                       \
            GLOAD_LDS(ks_ + koff[i],                    &smem[kdst[i]]);    \
            GLOAD_LDS(ks_ + koff[i] + 8192,             &smem[kdst[i] + 8192]); \
            GLOAD_LDS(vs_ + voff[i],                    &smem[vdst[i]]);    \
            GLOAD_LDS(vs_ + voff[i] + (size_t)128*4608, &smem[vdst[i] + 8192]); \
        }                                                                   \
    } while (0)

    // ---- compute one 32-key tile (byte-identical to R8's verified body) ----
    #define COMPUTE() do {                                                  \
        const unsigned char* kbuf = smem;                                   \
        const unsigned char* vbuf = smem + 16384;                           \
        f32x4 s00 = zz, s01 = zz, s10 = zz, s11 = zz;                       \
        __builtin_amdgcn_s_setprio(1);                                      \
        _Pragma("unroll")                                                   \
        for (int kc = 0; kc < 8; ++kc) {                                    \
            bf16x8 k0 = *reinterpret_cast<const bf16x8*>(kbuf + lr * 512        + ((lg * 16 + kc * 64) ^ kx)); \
            bf16x8 k1 = *reinterpret_cast<const bf16x8*>(kbuf + (lr + 16) * 512 + ((lg * 16 + kc * 64) ^ kx)); \
            s00 = __builtin_amdgcn_mfma_f32_16x16x32_bf16(k0, qa0[kc], s00, 0, 0, 0); \
            s01 = __builtin_amdgcn_mfma_f32_16x16x32_bf16(k1, qa0[kc], s01, 0, 0, 0); \
            s10 = __builtin_amdgcn_mfma_f32_16x16x32_bf16(k0, qa1[kc], s10, 0, 0, 0); \
            s11 = __builtin_amdgcn_mfma_f32_16x16x32_bf16(k1, qa1[kc], s11, 0, 0, 0); \
        }                                                                   \
        __builtin_amdgcn_s_setprio(0);                                      \
        bf16x8 pb0 = packP(s00, s01, sd0, ls0, lr, lg);                     \
        bf16x8 pb1 = packP(s10, s11, sd1, ls1, lr, lg);                     \
        __builtin_amdgcn_s_setprio(1);                                      \
        _Pragma("unroll")                                                   \
        for (int og = 0; og < 16; ++og) {                                   \
            bf16x8 vb = *reinterpret_cast<const bf16x8*>(vbuf + (og * 16 + lr) * 64 + vx); \
            acc0[og] = __builtin_amdgcn_mfma_f32_16x16x32_bf16(vb, pb0, acc0[og], 0, 0, 0); \
            acc1[og] = __builtin_amdgcn_mfma_f32_16x16x32_bf16(vb, pb1, acc1[og], 0, 0, 0); \
        }                                                                   \
        __builtin_amdgcn_s_setprio(0);                                      \
    } while (0)

    // prologue
    STAGE(0);
    __syncthreads();

    #pragma unroll 1
    for (int ti = 0; ti < nit; ++ti) {
        COMPUTE();
        __syncthreads();   // all waves done reading this tile
        if (ti + 1 < nit) STAGE(ti + 1);
        __syncthreads();   // staged data visible (vmcnt drained by syncthreads)
    }
    #undef STAGE
    #undef COMPUTE

    // reduce per-lane partial l over the 4 lane-groups (order-free: fixed shift)
    ls0 += __shfl_xor(ls0, 16); ls0 += __shfl_xor(ls0, 32);
    ls1 += __shfl_xor(ls1, 16); ls1 += __shfl_xor(ls1, 32);

    // write partials
    if (lg == 0) {
        pL[(size_t)(h * 8 + b) * NN + qbase + lr]      = ls0;
        pL[(size_t)(h * 8 + b) * NN + qbase + 16 + lr] = ls1;
    }
    // packed u32 store: within each 32-q chunk, u32 index lr holds (sub0, sub1)
    const size_t rowbase = (size_t)(h * 8 + b) * 256;
    const int ub = (qbase >> 1) + lr;   // u32 index within row
    #pragma unroll
    for (int og = 0; og < 16; ++og) {
        #pragma unroll
        for (int rr = 0; rr < 4; ++rr) {
            const int o = og * 16 + lg * 4 + rr;
            pA32[(rowbase + o) * (NN / 2) + ub] = pk2(acc0[og][rr], acc1[og][rr]);
        }
    }
}

// ---------------- Kernel M: out = (sum_c A_c)/(sum_c L_c) + bias + x  (vectorized) ----------------
__global__ __launch_bounds__(192) void kmerge(
    const unsigned* __restrict__ pA32, const float* __restrict__ pL,
    const float* __restrict__ x, const float* __restrict__ bias,
    float* __restrict__ out, int nsplit)
{
    const int b = blockIdx.x >> 8;
    const int o = blockIdx.x & 255;
    const float bo = bias[o];
    const size_t xb = ((size_t)b * 256 + o) * NN;
    #pragma unroll
    for (int k = 0; k < 3; ++k) {
        const int quad = k * 192 + threadIdx.x;   // 0..575
        const int n = quad * 4;
        const int ui = (n >> 5) * 16 + (n & 15);
        const int hi = (n >> 4) & 1;
        float v0 = 0.f, v1 = 0.f, v2 = 0.f, v3 = 0.f;
        float l0 = 0.f, l1 = 0.f, l2 = 0.f, l3 = 0.f;
        for (int c = 0; c < nsplit; ++c) {
            const size_t row = ((size_t)(c * 8 + b)) * 256 + o;
            u32x4 pv = *reinterpret_cast<const u32x4*>(pA32 + row * (NN / 2) + ui);
            v0 += bf2f((unsigned short)(hi ? (pv[0] >> 16) : (pv[0] & 0xffff)));
            v1 += bf2f((unsigned short)(hi ? (pv[1] >> 16) : (pv[1] & 0xffff)));
            v2 += bf2f((unsigned short)(hi ? (pv[2] >> 16) : (pv[2] & 0xffff)));
            v3 += bf2f((unsigned short)(hi ? (pv[3] >> 16) : (pv[3] & 0xffff)));
            float4 lv = *reinterpret_cast<const float4*>(pL + ((size_t)(c * 8 + b)) * NN + n);
            l0 += lv.x; l1 += lv.y; l2 += lv.z; l3 += lv.w;
        }
        float4 xv = *reinterpret_cast<const float4*>(x + xb + n);
        float4 ov;
        ov.x = v0 / l0 + bo + xv.x;
        ov.y = v1 / l1 + bo + xv.y;
        ov.z = v2 / l2 + bo + xv.z;
        ov.w = v3 / l3 + bo + xv.w;
        *reinterpret_cast<float4*>(out + xb + n) = ov;
    }
}

extern "C" void kernel_launch(void* const* d_in, const int* in_sizes, int n_in,
                              void* d_out, int out_size, void* d_ws, size_t ws_size,
                              hipStream_t stream) {
    const float* x    = (const float*)d_in[0];
    const float* Ww   = (const float*)d_in[1];
    const float* bias = (const float*)d_in[2];
    float* out = (float*)d_out;

    unsigned short* Xt  = (unsigned short*)d_ws;                 // B*N*C bf16   (9,437,184 B)
    unsigned short* Zc  = Xt + (size_t)BATCH * NN * CH;          // B*C*N bf16   (9,437,184 B)
    unsigned short* Wbf = Zc + (size_t)BATCH * NN * CH;          // C*C bf16     (131,072 B)
    unsigned*       pA32 = (unsigned*)(Wbf + (size_t)CH * CH);   // nsplit*B*C*(N/2) u32

    const size_t base = (size_t)9437184 * 2 + 131072;
    const size_t perSplit = (size_t)BATCH * CH * NN * 2   // pA
                          + (size_t)BATCH * NN * 4;       // pL
    int hshift;
    if (ws_size >= base + 4 * perSplit) hshift = 2;       // split-4 (nit=18)
    else                                hshift = 1;       // split-2 (nit=36)
    const int nsplit = 1 << hshift;
    float* pL = (float*)(pA32 + (size_t)nsplit * BATCH * CH * (NN / 2));

    ktrans<<<8 * 144 + 8,       256, 0, stream>>>(x, Ww, Xt, Wbf);
    kconv <<<288,               256, 0, stream>>>(Xt, Wbf, Zc);
    kattn <<<8 * 36 * nsplit,   128, 0, stream>>>(Xt, Zc, pA32, pL, hshift);
    kmerge<<<2048,              192, 0, stream>>>(pA32, pL, x, bias, out, nsplit);
}